// Round 8
// baseline (839.171 us; speedup 1.0000x reference)
//
#include <hip/hip_runtime.h>
#include <hip/hip_bf16.h>

#define Vn 25000
#define En 100000
#define NODE_IN 74
#define EDGE_IN 12
#define OUTD 64
#define EHID 128
#define NUM_STEPS 6

#define HPAD 68  // h16 row pitch (halves)

typedef __attribute__((ext_vector_type(8))) _Float16 half8;
typedef __attribute__((ext_vector_type(4))) float floatx4;

// h[v,o] = relu(node[v,:] @ Wp + bp)   [V,74]@[74,64]  (all fp32)
__global__ void proj_kernel(const float* __restrict__ node,
                            const float* __restrict__ Wp,
                            const float* __restrict__ bp,
                            float* __restrict__ h) {
  __shared__ float nf[NODE_IN];
  int v = blockIdx.x;
  int o = threadIdx.x;  // 64
  for (int i = o; i < NODE_IN; i += 64) nf[i] = node[(size_t)v * NODE_IN + i];
  __syncthreads();
  float acc = bp[o];
  for (int i = 0; i < NODE_IN; ++i) acc = fmaf(nf[i], Wp[i * OUTD + o], acc);
  h[(size_t)v * OUTD + o] = fmaxf(acc, 0.0f);
}

// f[e,k] = relu(edge[e,:] @ We1 + be1)   [E,12]@[12,128] fp32, stored f16
__global__ void edge_kernel(const float* __restrict__ ef,
                            const float* __restrict__ We1,
                            const float* __restrict__ be1,
                            _Float16* __restrict__ f) {
  __shared__ float es[EDGE_IN];
  int e = blockIdx.x;
  int k = threadIdx.x;  // 128
  if (k < EDGE_IN) es[k] = ef[(size_t)e * EDGE_IN + k];
  __syncthreads();
  float acc = be1[k];
  for (int j = 0; j < EDGE_IN; ++j) acc = fmaf(es[j], We1[j * EHID + k], acc);
  f[(size_t)e * EHID + k] = (_Float16)fmaxf(acc, 0.0f);
}

// SSTEP-contiguous + bank-swizzled B layout (f16).
// Logical index: g = step*2048 + c*512 + l15*32 + quad*8 + j, step = i*4+s,
// value = f16(We2[k = s*32+quad*8+j][col = i*64 + c*16 + l15]).
// Stored at step*2048 + (eidx ^ ((eidx>>6 & 3) << 3))  (quad ^= l15[2:1]):
// makes the per-stripe ds_read_b128 (16 lanes at 64B stride) hit all 32
// banks 2-way (free) instead of 8-way. global_load_lds stages each 4KB
// step-chunk linearly, so the swizzle is pre-baked in the global image
// and the reader applies the same XOR to its byte offset.
__global__ void w2r_kernel(const float* __restrict__ We2,
                           _Float16* __restrict__ w2s) {
  int g = blockIdx.x * 256 + threadIdx.x;  // < 524288 (logical index)
  int j = g & 7;
  int quad = (g >> 3) & 3;
  int l15 = (g >> 5) & 15;
  int c = (g >> 9) & 3;
  int step = g >> 11;     // 0..255
  int s = step & 3;
  int i = step >> 2;
  int k = s * 32 + quad * 8 + j;
  int col = i * 64 + c * 16 + l15;
  int eidx = g & 2047;
  int estore = eidx ^ (((eidx >> 6) & 3) << 3);
  w2s[((size_t)step << 11) | estore] = (_Float16)We2[(size_t)k * (OUTD * OUTD) + col];
}

#define GLOAD_LDS(gp, lp)                                                     \
  __builtin_amdgcn_global_load_lds(                                           \
      (const __attribute__((address_space(1))) void*)(gp),                    \
      (__attribute__((address_space(3))) void*)(lp), 16, 0, 0)

// Fused per-step message kernel, i-split across waves + register read-ahead:
// wave w accumulates over i in [16w,16w+16) for ALL 64 output cols. B streams
// global_load_lds -> per-wave 2-slot LDS ring -> REGISTERS one step ahead
// (bE/bO), so MFMAs never wait on fresh ds_reads. Slot-overwrite safety:
// counted lgkmcnt drains the slot's reads (issued a full KSTEP earlier)
// before the re-stage DMA is issued. h_t stored f16 (halves its LDS).
__global__ __launch_bounds__(256, 2) void msg_kernel(
    const float* __restrict__ h,
    const _Float16* __restrict__ f,
    const _Float16* __restrict__ w2s,
    const int* __restrict__ src,
    const int* __restrict__ dst,
    const float* __restrict__ be2,
    float* __restrict__ agg) {
  // [0,8704): h16[64][HPAD] f16; [8704,41472): per-wave B rings (4 x 8KB).
  // Epilogue overlays [0,32768) as reduce scratch (all dead by then).
  __shared__ __align__(16) char smem_raw[41472];
  __shared__ int s_dst[64];

  _Float16* h16 = (_Float16*)smem_raw;

  const int tid = threadIdx.x;
  const int wv = tid >> 6;        // wave 0..3 -> i-subset [16wv,16wv+16)
  const int lane = tid & 63;
  const int quad = lane >> 4;
  const int l15 = lane & 15;
  const int e0 = blockIdx.x * 64;

  if (tid < 64) {
    int e = e0 + tid;
    s_dst[tid] = (e < En) ? dst[e] : -1;
  }
  {
    int e = tid & 63;
    int ib = tid >> 6;  // i-block 0..3 (16 i's each)
    int eg = e0 + e;
    int sv = (eg < En) ? src[eg] : 0;
    const float4* hp = reinterpret_cast<const float4*>(h + (size_t)sv * OUTD + ib * 16);
    for (int c = 0; c < 4; ++c) {
      float4 val = hp[c];
      int i4 = ib * 16 + c * 4;
      h16[(i4 + 0) * HPAD + e] = (_Float16)val.x;
      h16[(i4 + 1) * HPAD + e] = (_Float16)val.y;
      h16[(i4 + 2) * HPAD + e] = (_Float16)val.z;
      h16[(i4 + 3) * HPAD + e] = (_Float16)val.w;
    }
  }
  __syncthreads();

  // A-fragments (f16): F rows for 4 row-tiles x 4 K-steps (i-invariant).
  // A[m=lane&15][k = s*32 + quad*8 + j]
  half8 afr[4][4];
#pragma unroll
  for (int t = 0; t < 4; ++t) {
    int e = e0 + t * 16 + l15;
    if (e >= En) e = En - 1;  // clamped rows suppressed at scatter
    const _Float16* fr = f + (size_t)e * EHID + quad * 8;
#pragma unroll
    for (int s = 0; s < 4; ++s)
      afr[t][s] = *reinterpret_cast<const half8*>(fr + s * 32);
  }

  floatx4 acc[4][4];  // [row-tile t][col-stripe c]
  const floatx4 zero4 = (floatx4){0.f, 0.f, 0.f, 0.f};
#pragma unroll
  for (int t = 0; t < 4; ++t)
#pragma unroll
    for (int c = 0; c < 4; ++c) acc[t][c] = zero4;

  const int ibase = wv * 16;

  // per-wave private ring: 2 slots x 4KB (slot0 = even steps, slot1 = odd)
  char* ring = smem_raw + 8704 + wv * 8192;
  const char* w2b = (const char*)w2s;
  // swizzled per-lane byte offset within a 4KB chunk (stripe c adds c*1024)
  const int roff = l15 * 64 + ((quad ^ ((l15 >> 1) & 3)) << 4);
  const char* slot0p = ring + roff;
  const char* slot1p = ring + 4096 + roff;

// stage global step GS (4KB) into ring slot SLOT: 4 x global_load_lds width-16
#define STAGE(GS, SLOT)                                                       \
  {                                                                           \
    const char* gp_ = w2b + (size_t)(GS) * 4096 + lane * 16;                  \
    char* lp_ = ring + (SLOT) * 4096;                                         \
    GLOAD_LDS(gp_, lp_);                                                      \
    GLOAD_LDS(gp_ + 1024, lp_ + 1024);                                        \
    GLOAD_LDS(gp_ + 2048, lp_ + 2048);                                        \
    GLOAD_LDS(gp_ + 3072, lp_ + 3072);                                        \
  }

#define VM4 asm volatile("s_waitcnt vmcnt(4)" ::: "memory")
#define VM0 asm volatile("s_waitcnt vmcnt(0)" ::: "memory")
#define LGKM0 asm volatile("s_waitcnt lgkmcnt(0)" ::: "memory")
#define LGKM4 asm volatile("s_waitcnt lgkmcnt(4)" ::: "memory")
#define SB __builtin_amdgcn_sched_barrier(0)

// KSTEP m: (1) LW drains the reads of the slot about to be re-staged
// (issued one KSTEP earlier -> nearly free; LGKM4 at ss0 spares the fresh
// hb reads, sound because lgkm retires in order and SB pins issue order),
// (2) re-stage step m+2 into the slot just consumed-from, (3) VW=vmcnt(4):
// in-order vmem retirement => step m+1's DMA (issued last KSTEP) landed,
// (4) ds_read step m+1 -> BNXT (background), (5) 16 MFMA on BCUR, already
// in registers since last KSTEP -> zero input wait.
#define KSTEP(SS, BCUR, BNXT, STSLOT, GST, LW, VW, DO_STAGE, DO_READ, RDP)    \
  {                                                                           \
    LW;                                                                       \
    SB;                                                                       \
    if (DO_STAGE) STAGE(GST, STSLOT);                                         \
    VW;                                                                       \
    if (DO_READ) {                                                            \
      BNXT[0] = *reinterpret_cast<const half8*>(RDP);                         \
      BNXT[1] = *reinterpret_cast<const half8*>(RDP + 1024);                  \
      BNXT[2] = *reinterpret_cast<const half8*>(RDP + 2048);                  \
      BNXT[3] = *reinterpret_cast<const half8*>(RDP + 3072);                  \
    }                                                                         \
    _Pragma("unroll") for (int t = 0; t < 4; ++t) {                           \
      half8 as = afr[t][SS] * hb[t];                                          \
      acc[t][0] = __builtin_amdgcn_mfma_f32_16x16x32_f16(as, BCUR[0], acc[t][0], 0, 0, 0); \
      acc[t][1] = __builtin_amdgcn_mfma_f32_16x16x32_f16(as, BCUR[1], acc[t][1], 0, 0, 0); \
      acc[t][2] = __builtin_amdgcn_mfma_f32_16x16x32_f16(as, BCUR[2], acc[t][2], 0, 0, 0); \
      acc[t][3] = __builtin_amdgcn_mfma_f32_16x16x32_f16(as, BCUR[3], acc[t][3], 0, 0, 0); \
    }                                                                         \
    SB;                                                                       \
  }

#define BUILD_HB(IV)                                                          \
  half8 hb[4];                                                                \
  _Pragma("unroll") for (int t = 0; t < 4; ++t) {                             \
    _Float16 hf = h16[(IV) * HPAD + t * 16 + l15];                            \
    hb[t] = (half8){hf, hf, hf, hf, hf, hf, hf, hf};                          \
  }

  // prologue: stage steps 0,1; wait step 0; read it into bE
  STAGE(ibase * 4, 0);
  STAGE(ibase * 4 + 1, 1);
  VM4;  // in-order retirement: leaves only the newest 4 (stage of step 1)
  half8 bE[4], bO[4];
  bE[0] = *reinterpret_cast<const half8*>(slot0p);
  bE[1] = *reinterpret_cast<const half8*>(slot0p + 1024);
  bE[2] = *reinterpret_cast<const half8*>(slot0p + 2048);
  bE[3] = *reinterpret_cast<const half8*>(slot0p + 3072);

  for (int ii = 0; ii < 15; ++ii) {
    int iv = ibase + ii;
    int gs = iv * 4;
    BUILD_HB(iv);
    KSTEP(0, bE, bO, 0, gs + 2, LGKM4, VM4, 1, 1, slot1p);
    KSTEP(1, bO, bE, 1, gs + 3, LGKM0, VM4, 1, 1, slot0p);
    KSTEP(2, bE, bO, 0, gs + 4, LGKM0, VM4, 1, 1, slot1p);
    KSTEP(3, bO, bE, 1, gs + 5, LGKM0, VM4, 1, 1, slot0p);
  }
  {  // peeled last i (local steps 60..63): stages 62,63 then drain
    int iv = ibase + 15;
    int gs = iv * 4;
    BUILD_HB(iv);
    KSTEP(0, bE, bO, 0, gs + 2, LGKM4, VM4, 1, 1, slot1p);
    KSTEP(1, bO, bE, 1, gs + 3, LGKM0, VM4, 1, 1, slot0p);
    KSTEP(2, bE, bO, 0, 0, LGKM0, VM0, 0, 1, slot1p);
    KSTEP(3, bO, bE, 1, 0, (void)0, (void)0, 0, 0, slot0p);
  }

  // be2 contribution (exact 0 here, kept for generality): wave 0 owns all
  // cols pre-reduction, so add sum_i h[e,i]*be2[i*64+o] on wave 0 only.
  if (wv == 0) {
#pragma unroll
    for (int s = 0; s < 2; ++s) {
      half8 b2f[4];
#pragma unroll
      for (int c = 0; c < 4; ++c) {
        half8 v;
#pragma unroll
        for (int j = 0; j < 8; ++j)
          v[j] = (_Float16)be2[(s * 32 + quad * 8 + j) * 64 + c * 16 + l15];
        b2f[c] = v;
      }
#pragma unroll
      for (int t = 0; t < 4; ++t) {
        half8 ha;
#pragma unroll
        for (int j = 0; j < 8; ++j)
          ha[j] = h16[(s * 32 + quad * 8 + j) * HPAD + t * 16 + l15];
#pragma unroll
        for (int c = 0; c < 4; ++c)
          acc[t][c] = __builtin_amdgcn_mfma_f32_16x16x32_f16(ha, b2f[c], acc[t][c], 0, 0, 0);
      }
    }
  }

  // ---- two-stage cross-wave reduce over i-quarters, then scatter.
  floatx4* scv = reinterpret_cast<floatx4*>(smem_raw);

#define ST1(TG)                                                           \
  _Pragma("unroll") for (int c = 0; c < 4; ++c)                           \
      scv[wv * 512 + (((TG) & 1) * 4 + c) * 64 + lane] = acc[TG][c];
#define LD1(TK)                                                           \
  _Pragma("unroll") for (int c = 0; c < 4; ++c)                           \
      acc[TK][c] += scv[(wv ^ 1) * 512 + (((TK) & 1) * 4 + c) * 64 + lane];
#define ST2(TG)                                                           \
  _Pragma("unroll") for (int c = 0; c < 4; ++c)                           \
      scv[wv * 512 + c * 64 + lane] = acc[TG][c];
#define LD2(TK)                                                           \
  _Pragma("unroll") for (int c = 0; c < 4; ++c)                           \
      acc[TK][c] += scv[(wv ^ 2) * 512 + c * 64 + lane];
#define SCAT(TF)                                                          \
  {                                                                       \
    int rb = (TF) * 16 + quad * 4;                                        \
    _Pragma("unroll") for (int c = 0; c < 4; ++c) {                       \
      int col = c * 16 + l15;                                             \
      _Pragma("unroll") for (int r = 0; r < 4; ++r) {                     \
        int d = s_dst[rb + r];                                            \
        if (d >= 0) atomicAdd(&agg[(size_t)d * OUTD + col], acc[TF][c][r]); \
      }                                                                   \
    }                                                                     \
  }

  __syncthreads();  // h16 and rings dead from here; smem becomes scratch
  // stage 1: pairs (0,1),(2,3). even wave keeps rows t{0,1}, odd keeps t{2,3}
  if ((wv & 1) == 0) { ST1(2); ST1(3); } else { ST1(0); ST1(1); }
  __syncthreads();
  if ((wv & 1) == 0) { LD1(0); LD1(1); } else { LD1(2); LD1(3); }
  __syncthreads();
  // stage 2: pairs (0,2),(1,3). final tile: w0->t0, w2->t1, w1->t2, w3->t3
  if (wv == 0) { ST2(1); } else if (wv == 1) { ST2(3); }
  else if (wv == 2) { ST2(0); } else { ST2(2); }
  __syncthreads();
  if (wv == 0) { LD2(0); SCAT(0); }
  else if (wv == 1) { LD2(2); SCAT(2); }
  else if (wv == 2) { LD2(1); SCAT(1); }
  else { LD2(3); SCAT(3); }
}

// h_out = relu(agg + bias); re-zero agg; last step also writes fp32 d_out
__global__ void update_kernel(float* __restrict__ agg,
                              const float* __restrict__ bias,
                              float* __restrict__ hout,
                              float* __restrict__ dout, int last) {
  int g = blockIdx.x * 256 + threadIdx.x;
  if (g >= Vn * OUTD) return;
  float v = agg[g];
  agg[g] = 0.0f;
  float r = fmaxf(v + bias[g & 63], 0.0f);
  hout[g] = r;
  if (last) dout[g] = r;
}

extern "C" void kernel_launch(void* const* d_in, const int* in_sizes, int n_in,
                              void* d_out, int out_size, void* d_ws, size_t ws_size,
                              hipStream_t stream) {
  const float* node = (const float*)d_in[0];
  const float* edge = (const float*)d_in[1];
  const int* src = (const int*)d_in[2];
  const int* dst = (const int*)d_in[3];
  const float* Wp   = (const float*)d_in[4];
  const float* bp   = (const float*)d_in[5];
  const float* We1  = (const float*)d_in[6];
  const float* be1  = (const float*)d_in[7];
  const float* We2  = (const float*)d_in[8];
  const float* be2  = (const float*)d_in[9];
  const float* bias = (const float*)d_in[10];
  float* out = (float*)d_out;

  char* ws = (char*)d_ws;
  float* agg = (float*)(ws);                        // 6,400,000 B
  float* h_a = (float*)(ws + 6400000);              // 6,400,000 B
  float* h_b = (float*)(ws + 12800000);             // 6,400,000 B
  _Float16* f   = (_Float16*)(ws + 19200000);       // 25,600,000 B
  _Float16* w2s = (_Float16*)(ws + 44800000);       // 1,048,576 B

  hipMemsetAsync(agg, 0, (size_t)Vn * OUTD * sizeof(float), stream);
  proj_kernel<<<Vn, 64, 0, stream>>>(node, Wp, bp, h_a);
  edge_kernel<<<En, 128, 0, stream>>>(edge, We1, be1, f);
  w2r_kernel<<<(OUTD * OUTD * EHID) / 256, 256, 0, stream>>>(We2, w2s);

  float* hin = h_a;
  float* hout = h_b;
  for (int s = 0; s < NUM_STEPS; ++s) {
    msg_kernel<<<(En + 63) / 64, 256, 0, stream>>>(hin, f, w2s, src, dst, be2, agg);
    update_kernel<<<(Vn * OUTD + 255) / 256, 256, 0, stream>>>(
        agg, bias, hout, out, s == NUM_STEPS - 1);
    float* t = hin; hin = hout; hout = t;
  }
}